// Round 22
// baseline (76.650 us; speedup 1.0000x reference)
//
#include <hip/hip_runtime.h>
#include <hip/hip_bf16.h>

// ---------------- constants ----------------
#define B_SZ   256
#define L_SZ   1024
#define C_SZ   64
#define HID    256
#define KQ     24576
#define WIN    125
#define WSTART (L_SZ - WIN)

// output offsets (floats)
#define OFF_LOGITS_S   0LL
#define OFF_LABELS_S   6356992LL
#define OFF_LOGITS_T   6357248LL
#define OFF_LABELS_T   12714240LL
#define OFF_LOGITS_TS  12714496LL
#define OFF_LABELS_TS  12780032LL
#define OFF_PRED_DOM   12780288LL
#define OFF_LABELS_DOM 12780800LL
#define OFF_YS         12781312LL

#define INV_T (1.0f / 0.07f)

typedef __attribute__((ext_vector_type(8))) short  bf16x8;
typedef __attribute__((ext_vector_type(4))) float  floatx4;
typedef __attribute__((ext_vector_type(16))) float floatx16;
typedef __attribute__((ext_vector_type(4))) unsigned short ushortx4;

__device__ __forceinline__ unsigned short f2bf_rne(float x) {
    unsigned u = __float_as_uint(x);
    unsigned r = u + 0x7fffu + ((u >> 16) & 1u);
    return (unsigned short)(r >> 16);
}
__device__ __forceinline__ float bf2f(unsigned short h) {
    return __uint_as_float(((unsigned)h) << 16);
}

__device__ __forceinline__ int swz2(int r) { return ((r >> 1) & 7) << 4; }

// verified R18 DPP tap1 derivation
__device__ __forceinline__ bf16x8 dpp_tap1(bf16x8 f0, bf16x8 f2) {
    union U { bf16x8 v; int d[4]; } a, b, r;
    a.v = f0; b.v = f2;
#pragma unroll
    for (int k = 0; k < 4; ++k) {
        int patch = __builtin_amdgcn_update_dpp(0, b.d[k], 0x111, 0xf, 0xf, false);     // row_shr:1
        r.d[k]    = __builtin_amdgcn_update_dpp(patch, a.d[k], 0x101, 0xf, 0xf, false); // row_shl:1
    }
    return r.v;
}

// ---------------- weight A-fragment prep (16x16x32 layout) ----------------
__global__ void prep_frag_kernel(const float* __restrict__ c1w,
                                 const float* __restrict__ c2w,
                                 unsigned short* __restrict__ wf) {
    int bid = blockIdx.x;
    int kb = bid & 1, mt = (bid >> 1) & 3;
    int sttap = bid >> 3;
    int tap = sttap % 3, st = sttap / 3;
    int l = st >> 1, cv = st & 1;
    int tid = threadIdx.x;
    int j = tid & 7, lane = tid >> 3;
    int co = mt * 16 + (lane & 15);
    int ci = kb * 32 + (lane >> 4) * 8 + j;
    const float* src = cv ? c2w : c1w;
    float w = src[((l * 64 + co) * 64 + ci) * 3 + tap];
    unsigned short hi = f2bf_rne(w);
    unsigned short lo = f2bf_rne(w - bf2f(hi));
    size_t b0 = ((((size_t)((st * 3 + tap) * 2 + 0)) * 4 + mt) * 2 + kb) * 512 + lane * 8 + j;
    size_t b1 = ((((size_t)((st * 3 + tap) * 2 + 1)) * 4 + mt) * 2 + kb) * 512 + lane * 8 + j;
    wf[b0] = hi;
    wf[b1] = lo;
}

// ---------------- heavy-path layout (NH=2) ----------------
#define R0H 0
#define R0L 16384
#define R1H 32768
#define R1L 40960
#define HHB 49152
#define HLB 65536
#define SCRATCH_B 57344

// ---------------- light-dual layout (NH=1, 2 items) ----------------
#define L_IT   39808
#define L_X0   0        // 125 rows
#define L_R1   16000    // 61 rows
#define L_HH   23808    // 123 rows
#define L_SCR  39552    // 64 floats

template<int NH>
__device__ __forceinline__ void loadAx(bf16x8 A[3][NH][2], const bf16x8* __restrict__ wf8,
                                       int st, int mt, int lane) {
#pragma unroll
    for (int tap = 0; tap < 3; ++tap)
#pragma unroll
        for (int h = 0; h < NH; ++h)
#pragma unroll
            for (int kb = 0; kb < 2; ++kb)
                A[tap][h][kb] = wf8[((((st * 3 + tap) * 2 + h) * 4 + mt) * 2 + kb) * 64 + lane];
}

template<int NH>
__device__ __forceinline__ void copyAx(bf16x8 D[3][NH][2], const bf16x8 S[3][NH][2]) {
#pragma unroll
    for (int tap = 0; tap < 3; ++tap)
#pragma unroll
        for (int h = 0; h < NH; ++h)
#pragma unroll
            for (int kb = 0; kb < 2; ++kb)
                D[tap][h][kb] = S[tap][h][kb];
}

// ================= heavy conv pass (NH=2, byte-identical semantics to R20) =================
template<int TILES, bool RES, bool FINAL, bool DPP1>
__device__ __forceinline__ void conv_pass(
    char* lds, const bf16x8 A[3][2][2],
    int inH, int inL, int rows_valid, int stride,
    int outH, int outL, int n_out,
    int resH, int resL, int res_valid,
    const float* __restrict__ bias,
    int mt, int lg, int li)
{
    int co0 = mt * 16 + lg * 4;
    float4 b4 = *(const float4*)(bias + co0);
    float ba[4] = {b4.x, b4.y, b4.z, b4.w};

#pragma unroll
    for (int tt = 0; tt < TILES; ++tt) {
        int i = tt * 16 + li;
        floatx4 acc = {0.f, 0.f, 0.f, 0.f};
        if (DPP1) {
            int jr0 = i;       jr0 = (jr0 < rows_valid - 1) ? jr0 : (rows_valid - 1);
            int jr2 = i + 2;   jr2 = (jr2 < rows_valid - 1) ? jr2 : (rows_valid - 1);
            int sw0 = swz2(jr0), sw2 = swz2(jr2);
#pragma unroll
            for (int kb = 0; kb < 2; ++kb) {
                int cbase = kb * 64 + lg * 16;
                bf16x8 bH0 = *(const bf16x8*)(lds + inH + jr0 * 128 + (cbase ^ sw0));
                bf16x8 bH2 = *(const bf16x8*)(lds + inH + jr2 * 128 + (cbase ^ sw2));
                bf16x8 bH1 = dpp_tap1(bH0, bH2);
                bf16x8 bL0 = *(const bf16x8*)(lds + inL + jr0 * 128 + (cbase ^ sw0));
                bf16x8 bL2 = *(const bf16x8*)(lds + inL + jr2 * 128 + (cbase ^ sw2));
                bf16x8 bL1 = dpp_tap1(bL0, bL2);
                acc = __builtin_amdgcn_mfma_f32_16x16x32_bf16(A[0][0][kb], bH0, acc, 0, 0, 0);
                acc = __builtin_amdgcn_mfma_f32_16x16x32_bf16(A[0][0][kb], bL0, acc, 0, 0, 0);
                acc = __builtin_amdgcn_mfma_f32_16x16x32_bf16(A[0][1][kb], bH0, acc, 0, 0, 0);
                acc = __builtin_amdgcn_mfma_f32_16x16x32_bf16(A[1][0][kb], bH1, acc, 0, 0, 0);
                acc = __builtin_amdgcn_mfma_f32_16x16x32_bf16(A[1][0][kb], bL1, acc, 0, 0, 0);
                acc = __builtin_amdgcn_mfma_f32_16x16x32_bf16(A[1][1][kb], bH1, acc, 0, 0, 0);
                acc = __builtin_amdgcn_mfma_f32_16x16x32_bf16(A[2][0][kb], bH2, acc, 0, 0, 0);
                acc = __builtin_amdgcn_mfma_f32_16x16x32_bf16(A[2][0][kb], bL2, acc, 0, 0, 0);
                acc = __builtin_amdgcn_mfma_f32_16x16x32_bf16(A[2][1][kb], bH2, acc, 0, 0, 0);
            }
        } else {
#pragma unroll
            for (int tap = 0; tap < 3; ++tap) {
                int jr = i * stride + tap;
                jr = (jr < rows_valid - 1) ? jr : (rows_valid - 1);
                int sw = swz2(jr);
                const char* pH = lds + inH + jr * 128;
                const char* pL = lds + inL + jr * 128;
#pragma unroll
                for (int kb = 0; kb < 2; ++kb) {
                    int cb = (kb * 64 + lg * 16) ^ sw;
                    bf16x8 bH = *(const bf16x8*)(pH + cb);
                    bf16x8 bL = *(const bf16x8*)(pL + cb);
                    acc = __builtin_amdgcn_mfma_f32_16x16x32_bf16(A[tap][0][kb], bH, acc, 0, 0, 0);
                    acc = __builtin_amdgcn_mfma_f32_16x16x32_bf16(A[tap][0][kb], bL, acc, 0, 0, 0);
                    acc = __builtin_amdgcn_mfma_f32_16x16x32_bf16(A[tap][1][kb], bH, acc, 0, 0, 0);
                }
            }
        }
        float v[4];
#pragma unroll
        for (int r = 0; r < 4; ++r) v[r] = fmaxf(acc[r] + ba[r], 0.f);
        if (RES) {
            int rr = 2 * i + 4;
            rr = (rr < res_valid - 1) ? rr : (res_valid - 1);
            int rcb = (mt * 32 + lg * 8) ^ swz2(rr);
            ushortx4 rh = *(const ushortx4*)(lds + resH + rr * 128 + rcb);
            ushortx4 rl = *(const ushortx4*)(lds + resL + rr * 128 + rcb);
#pragma unroll
            for (int r = 0; r < 4; ++r)
                v[r] = fmaxf(v[r] + bf2f(rh[r]) + bf2f(rl[r]), 0.f);
        }
        if (FINAL) {
            if (i == 0) {
                float* scratch = (float*)(lds + SCRATCH_B);
#pragma unroll
                for (int r = 0; r < 4; ++r) scratch[co0 + r] = v[r];
            }
        } else if (i < n_out) {
            int wcb = (mt * 32 + lg * 8) ^ swz2(i);
            ushortx4 h4, l4;
#pragma unroll
            for (int r = 0; r < 4; ++r) {
                h4[r] = f2bf_rne(v[r]);
                l4[r] = f2bf_rne(v[r] - bf2f(h4[r]));
            }
            *(ushortx4*)(lds + outH + i * 128 + wcb) = h4;
            *(ushortx4*)(lds + outL + i * 128 + wcb) = l4;
        }
    }
}

__device__ __forceinline__ void encode_body_heavy(
    char* lds, const float* __restrict__ base,
    const bf16x8* __restrict__ wf8,
    const float* __restrict__ c1b, const float* __restrict__ c2b,
    int tid, int mt, int lane, int lg, int li)
{
    const float4* base4 = reinterpret_cast<const float4*>(base);
    bf16x8 A[3][2][2], An[3][2][2];
    loadAx<2>(A, wf8, 0, mt, lane);

    for (int idx = tid; idx < 2000; idx += 256) {
        float4 v = base4[idx];
        int t = idx >> 4, c0 = (idx & 15) * 4;
        int cb = (c0 * 2) ^ swz2(t);
        float vv[4] = {v.x, v.y, v.z, v.w};
        ushortx4 h4, l4;
#pragma unroll
        for (int r = 0; r < 4; ++r) {
            h4[r] = f2bf_rne(vv[r]);
            l4[r] = f2bf_rne(vv[r] - bf2f(h4[r]));
        }
        *(ushortx4*)(lds + R0H + t * 128 + cb) = h4;
        *(ushortx4*)(lds + R0L + t * 128 + cb) = l4;
    }
    __syncthreads();

    loadAx<2>(An, wf8, 1, mt, lane);
    conv_pass<8, false, false, true>(lds, A, R0H, R0L, 125, 1, HHB, HLB, 123, 0, 0, 0,
                                     c1b + 0, mt, lg, li);
    __syncthreads();
    copyAx<2>(A, An); loadAx<2>(An, wf8, 2, mt, lane);
    conv_pass<4, true, false, false>(lds, A, HHB, HLB, 123, 2, R1H, R1L, 61, R0H, R0L, 125,
                                     c2b + 0, mt, lg, li);
    __syncthreads();
    copyAx<2>(A, An);
    loadAx<2>(An, wf8, 3, mt, lane);
    conv_pass<4, false, false, true>(lds, A, R1H, R1L, 61, 1, HHB, HLB, 59, 0, 0, 0,
                                     c1b + 64, mt, lg, li);
    __syncthreads();
    copyAx<2>(A, An); loadAx<2>(An, wf8, 4, mt, lane);
    conv_pass<2, true, false, false>(lds, A, HHB, HLB, 59, 2, R0H, R0L, 29, R1H, R1L, 61,
                                     c2b + 64, mt, lg, li);
    __syncthreads();
    copyAx<2>(A, An);
    loadAx<2>(An, wf8, 5, mt, lane);
    conv_pass<2, false, false, true>(lds, A, R0H, R0L, 29, 1, HHB, HLB, 27, 0, 0, 0,
                                     c1b + 128, mt, lg, li);
    __syncthreads();
    copyAx<2>(A, An); loadAx<2>(An, wf8, 6, mt, lane);
    conv_pass<1, true, false, false>(lds, A, HHB, HLB, 27, 2, R1H, R1L, 13, R0H, R0L, 29,
                                     c2b + 128, mt, lg, li);
    __syncthreads();
    copyAx<2>(A, An);
    loadAx<2>(An, wf8, 7, mt, lane);
    conv_pass<1, false, false, true>(lds, A, R1H, R1L, 13, 1, HHB, HLB, 11, 0, 0, 0,
                                     c1b + 192, mt, lg, li);
    __syncthreads();
    copyAx<2>(A, An); loadAx<2>(An, wf8, 8, mt, lane);
    conv_pass<1, true, false, false>(lds, A, HHB, HLB, 11, 2, R0H, R0L, 5, R1H, R1L, 13,
                                     c2b + 192, mt, lg, li);
    __syncthreads();
    copyAx<2>(A, An);
    loadAx<2>(An, wf8, 9, mt, lane);
    conv_pass<1, false, false, true>(lds, A, R0H, R0L, 5, 1, HHB, HLB, 3, 0, 0, 0,
                                     c1b + 256, mt, lg, li);
    __syncthreads();
    copyAx<2>(A, An);
    conv_pass<1, true, true, false>(lds, A, HHB, HLB, 3, 2, R1H, R1L, 1, R0H, R0L, 5,
                                    c2b + 256, mt, lg, li);
    __syncthreads();
}

// ================= light-dual conv pass (NH=1, 2 items per block) =================
template<int TILES, bool RES, bool FINAL, bool DPP1>
__device__ __forceinline__ void conv_pass_l2(
    char* lds, const bf16x8 A[3][1][2],
    int inO, int rows_valid, int stride,
    int outO, int n_out,
    int resO, int res_valid,
    const float* __restrict__ bias,
    int mt, int lg, int li)
{
    int co0 = mt * 16 + lg * 4;
    float4 b4 = *(const float4*)(bias + co0);
    float ba[4] = {b4.x, b4.y, b4.z, b4.w};

#pragma unroll
    for (int it = 0; it < 2; ++it) {
        char* L = lds + it * L_IT;
#pragma unroll
        for (int tt = 0; tt < TILES; ++tt) {
            int i = tt * 16 + li;
            floatx4 acc = {0.f, 0.f, 0.f, 0.f};
            if (DPP1) {
                int jr0 = i;       jr0 = (jr0 < rows_valid - 1) ? jr0 : (rows_valid - 1);
                int jr2 = i + 2;   jr2 = (jr2 < rows_valid - 1) ? jr2 : (rows_valid - 1);
                int sw0 = swz2(jr0), sw2 = swz2(jr2);
#pragma unroll
                for (int kb = 0; kb < 2; ++kb) {
                    int cbase = kb * 64 + lg * 16;
                    bf16x8 bH0 = *(const bf16x8*)(L + inO + jr0 * 128 + (cbase ^ sw0));
                    bf16x8 bH2 = *(const bf16x8*)(L + inO + jr2 * 128 + (cbase ^ sw2));
                    bf16x8 bH1 = dpp_tap1(bH0, bH2);
                    acc = __builtin_amdgcn_mfma_f32_16x16x32_bf16(A[0][0][kb], bH0, acc, 0, 0, 0);
                    acc = __builtin_amdgcn_mfma_f32_16x16x32_bf16(A[1][0][kb], bH1, acc, 0, 0, 0);
                    acc = __builtin_amdgcn_mfma_f32_16x16x32_bf16(A[2][0][kb], bH2, acc, 0, 0, 0);
                }
            } else {
#pragma unroll
                for (int tap = 0; tap < 3; ++tap) {
                    int jr = i * stride + tap;
                    jr = (jr < rows_valid - 1) ? jr : (rows_valid - 1);
                    int sw = swz2(jr);
#pragma unroll
                    for (int kb = 0; kb < 2; ++kb) {
                        int cb = (kb * 64 + lg * 16) ^ sw;
                        bf16x8 bH = *(const bf16x8*)(L + inO + jr * 128 + cb);
                        acc = __builtin_amdgcn_mfma_f32_16x16x32_bf16(A[tap][0][kb], bH, acc, 0, 0, 0);
                    }
                }
            }
            float v[4];
#pragma unroll
            for (int r = 0; r < 4; ++r) v[r] = fmaxf(acc[r] + ba[r], 0.f);
            if (RES) {
                int rr = 2 * i + 4;
                rr = (rr < res_valid - 1) ? rr : (res_valid - 1);
                int rcb = (mt * 32 + lg * 8) ^ swz2(rr);
                ushortx4 rh = *(const ushortx4*)(L + resO + rr * 128 + rcb);
#pragma unroll
                for (int r = 0; r < 4; ++r)
                    v[r] = fmaxf(v[r] + bf2f(rh[r]), 0.f);
            }
            if (FINAL) {
                if (i == 0) {
                    float* scratch = (float*)(L + L_SCR);
#pragma unroll
                    for (int r = 0; r < 4; ++r) scratch[co0 + r] = v[r];
                }
            } else if (i < n_out) {
                int wcb = (mt * 32 + lg * 8) ^ swz2(i);
                ushortx4 h4;
#pragma unroll
                for (int r = 0; r < 4; ++r) h4[r] = f2bf_rne(v[r]);
                *(ushortx4*)(L + outO + i * 128 + wcb) = h4;
            }
        }
    }
}

__device__ __forceinline__ void encode_body_light2(
    char* lds, const float* __restrict__ base0, const float* __restrict__ base1,
    const bf16x8* __restrict__ wf8,
    const float* __restrict__ c1b, const float* __restrict__ c2b,
    int tid, int mt, int lane, int lg, int li)
{
    const float* bases[2] = {base0, base1};
#pragma unroll
    for (int it = 0; it < 2; ++it) {
        const float4* base4 = reinterpret_cast<const float4*>(bases[it]);
        char* L = lds + it * L_IT;
        for (int idx = tid; idx < 2000; idx += 256) {
            float4 v = base4[idx];
            int t = idx >> 4, c0 = (idx & 15) * 4;
            int cb = (c0 * 2) ^ swz2(t);
            float vv[4] = {v.x, v.y, v.z, v.w};
            ushortx4 h4;
#pragma unroll
            for (int r = 0; r < 4; ++r) h4[r] = f2bf_rne(vv[r]);
            *(ushortx4*)(L + L_X0 + t * 128 + cb) = h4;
        }
    }
    __syncthreads();

    bf16x8 A[3][1][2], An[3][1][2];
    loadAx<1>(A, wf8, 0, mt, lane);
    loadAx<1>(An, wf8, 1, mt, lane);
    conv_pass_l2<8, false, false, true>(lds, A, L_X0, 125, 1, L_HH, 123, 0, 0,
                                        c1b + 0, mt, lg, li);
    __syncthreads();
    copyAx<1>(A, An); loadAx<1>(An, wf8, 2, mt, lane);
    conv_pass_l2<4, true, false, false>(lds, A, L_HH, 123, 2, L_R1, 61, L_X0, 125,
                                        c2b + 0, mt, lg, li);
    __syncthreads();
    copyAx<1>(A, An);
    loadAx<1>(An, wf8, 3, mt, lane);
    conv_pass_l2<4, false, false, true>(lds, A, L_R1, 61, 1, L_HH, 59, 0, 0,
                                        c1b + 64, mt, lg, li);
    __syncthreads();
    copyAx<1>(A, An); loadAx<1>(An, wf8, 4, mt, lane);
    conv_pass_l2<2, true, false, false>(lds, A, L_HH, 59, 2, L_X0, 29, L_R1, 61,
                                        c2b + 64, mt, lg, li);
    __syncthreads();
    copyAx<1>(A, An);
    loadAx<1>(An, wf8, 5, mt, lane);
    conv_pass_l2<2, false, false, true>(lds, A, L_X0, 29, 1, L_HH, 27, 0, 0,
                                        c1b + 128, mt, lg, li);
    __syncthreads();
    copyAx<1>(A, An); loadAx<1>(An, wf8, 6, mt, lane);
    conv_pass_l2<1, true, false, false>(lds, A, L_HH, 27, 2, L_R1, 13, L_X0, 29,
                                        c2b + 128, mt, lg, li);
    __syncthreads();
    copyAx<1>(A, An);
    loadAx<1>(An, wf8, 7, mt, lane);
    conv_pass_l2<1, false, false, true>(lds, A, L_R1, 13, 1, L_HH, 11, 0, 0,
                                        c1b + 192, mt, lg, li);
    __syncthreads();
    copyAx<1>(A, An); loadAx<1>(An, wf8, 8, mt, lane);
    conv_pass_l2<1, true, false, false>(lds, A, L_HH, 11, 2, L_X0, 5, L_R1, 13,
                                        c2b + 192, mt, lg, li);
    __syncthreads();
    copyAx<1>(A, An);
    loadAx<1>(An, wf8, 9, mt, lane);
    conv_pass_l2<1, false, false, true>(lds, A, L_X0, 5, 1, L_HH, 3, 0, 0,
                                        c1b + 256, mt, lg, li);
    __syncthreads();
    copyAx<1>(A, An);
    conv_pass_l2<1, true, true, false>(lds, A, L_HH, 3, 2, L_R1, 1, L_X0, 5,
                                       c2b + 256, mt, lg, li);
    __syncthreads();
}

__launch_bounds__(256)
__global__ void encode_kernel(const float* __restrict__ sqs, const float* __restrict__ sks,
                              const float* __restrict__ sqt, const float* __restrict__ skt,
                              const unsigned short* __restrict__ wf,
                              const float* __restrict__ c1b, const float* __restrict__ c2b,
                              const float* __restrict__ pjw1, const float* __restrict__ pjb1,
                              const float* __restrict__ pjw2, const float* __restrict__ pjb2,
                              float* __restrict__ enc, float* __restrict__ proj,
                              unsigned short* __restrict__ pbf) {
    __shared__ char lds[81920];
    int b = blockIdx.x;
    int by = blockIdx.y;                 // 0: s=0 heavy, 1: s=3 heavy, 2: s=1+2 light dual
    int tid = threadIdx.x;
    int mt   = tid >> 6;
    int lane = tid & 63;
    int lg = lane >> 4, li = lane & 15;
    const bf16x8* wf8 = (const bf16x8*)wf;

    if (by < 2) {
        int s = by ? 3 : 0;
        const float* seq = (s == 0) ? sqs : skt;
        const float* base = seq + ((size_t)b * L_SZ + WSTART) * C_SZ;
        encode_body_heavy(lds, base, wf8, c1b, c2b, tid, mt, lane, lg, li);

        float* xn = (float*)(lds + R0H);
        if (tid < 64) {
            float vv = ((float*)(lds + SCRATCH_B))[tid];
            float sq = vv * vv;
#pragma unroll
            for (int off = 32; off; off >>= 1) sq += __shfl_xor(sq, off, 64);
            float norm = fmaxf(sqrtf(sq), 1e-12f);
            float nv = vv / norm;
            enc[((size_t)s * B_SZ + b) * 64 + tid] = nv;
            xn[tid] = nv;
        }
        __syncthreads();

        if (s == 0) {
            float* hv   = (float*)(lds + R1H);
            float* red4 = (float*)(lds + R1H + 1024);
            {
                float acc = pjb1[tid];
                const float* wcol = pjw1 + tid;
                for (int c = 0; c < 64; ++c) acc = fmaf(xn[c], wcol[c * 256], acc);
                hv[tid] = fmaxf(acc, 0.f);
            }
            __syncthreads();
            {
                int wv = tid >> 6, o = tid & 63;
                float acc = 0.f;
                const float* wcol = pjw2 + o;
                int j0 = wv * 64;
                for (int j = j0; j < j0 + 64; ++j) acc = fmaf(hv[j], wcol[j * 64], acc);
                red4[wv * 64 + o] = acc;
            }
            __syncthreads();
            if (tid < 64) {
                float o = pjb2[tid];
#pragma unroll
                for (int k = 0; k < 4; ++k) o += red4[k * 64 + tid];
                float sq = o * o;
#pragma unroll
                for (int off = 32; off; off >>= 1) sq += __shfl_xor(sq, off, 64);
                float norm = fmaxf(sqrtf(sq), 1e-12f);
                float pv = o / norm;
                proj[((size_t)0 * B_SZ + b) * 64 + tid] = pv;
                pbf[((size_t)0 * B_SZ + b) * 64 + tid] = f2bf_rne(pv);
            }
        }
    } else {
        // light dual: item0 = (s=1, sks), item1 = (s=2, sqt)
        const float* base0 = sks + ((size_t)b * L_SZ + WSTART) * C_SZ;
        const float* base1 = sqt + ((size_t)b * L_SZ + WSTART) * C_SZ;
        encode_body_light2(lds, base0, base1, wf8, c1b, c2b, tid, mt, lane, lg, li);

        // norms: wave0 -> item0 (s=1), wave1 -> item1 (s=2)
        float* xn2 = (float*)(lds + 0);      // item0 X0 region, dead; holds s=2 xn for proj
        int itw = tid >> 6;
        if (itw < 2) {
            float* scr = (float*)(lds + itw * L_IT + L_SCR);
            float vv = scr[lane];
            float sq = vv * vv;
#pragma unroll
            for (int off = 32; off; off >>= 1) sq += __shfl_xor(sq, off, 64);
            float norm = fmaxf(sqrtf(sq), 1e-12f);
            float nv = vv / norm;
            int s_ = (itw == 0) ? 1 : 2;
            enc[((size_t)s_ * B_SZ + b) * 64 + lane] = nv;
            if (itw == 1) xn2[lane] = nv;
        }
        __syncthreads();

        // proj for item1 (s=2)
        float* hv   = (float*)(lds + 1024);
        float* red4 = (float*)(lds + 2048);
        {
            float acc = pjb1[tid];
            const float* wcol = pjw1 + tid;
            for (int c = 0; c < 64; ++c) acc = fmaf(xn2[c], wcol[c * 256], acc);
            hv[tid] = fmaxf(acc, 0.f);
        }
        __syncthreads();
        {
            int wv = tid >> 6, o = tid & 63;
            float acc = 0.f;
            const float* wcol = pjw2 + o;
            int j0 = wv * 64;
            for (int j = j0; j < j0 + 64; ++j) acc = fmaf(hv[j], wcol[j * 64], acc);
            red4[wv * 64 + o] = acc;
        }
        __syncthreads();
        if (tid < 64) {
            float o = pjb2[tid];
#pragma unroll
            for (int k = 0; k < 4; ++k) o += red4[k * 64 + tid];
            float sq = o * o;
#pragma unroll
            for (int off = 32; off; off >>= 1) sq += __shfl_xor(sq, off, 64);
            float norm = fmaxf(sqrtf(sq), 1e-12f);
            float pv = o / norm;
            proj[((size_t)1 * B_SZ + b) * 64 + tid] = pv;
            pbf[((size_t)1 * B_SZ + b) * 64 + tid] = f2bf_rne(pv);
        }
    }
}

// ---------------- logits + heads fused kernel (unchanged from R20) ----------------
__launch_bounds__(512)
__global__ void qlogits_kernel(const float* __restrict__ proj,
                               const unsigned short* __restrict__ pbf,
                               const float* __restrict__ enc,
                               const float* __restrict__ queue_s, const float* __restrict__ queue_t,
                               const float* __restrict__ stat,
                               const float* __restrict__ dw1, const float* __restrict__ db1,
                               const float* __restrict__ dw2, const float* __restrict__ db2,
                               const float* __restrict__ prw1, const float* __restrict__ prb1,
                               const float* __restrict__ prw2, const float* __restrict__ prb2,
                               float* __restrict__ out) {
    __shared__ char lds[8448];
    int bx = blockIdx.x;
    int sz = blockIdx.y;
    int tid = threadIdx.x;
    long long outBase0 = (sz == 0) ? OFF_LOGITS_S : OFF_LOGITS_T;

    if (bx >= 392) {
        int hb = (bx - 392) + sz * 513;
        if (hb < 256) {
            __shared__ float kt[64];
            __shared__ float qt[64];
            __shared__ float swv[8];
            __shared__ int   swj[8];
            int i = hb;
            if (tid < 64) {
                kt[tid] = enc[((size_t)3 * B_SZ + i) * 64 + tid];
                qt[tid] = enc[((size_t)2 * B_SZ + i) * 64 + tid];
            }
            __syncthreads();
            float bv = 1e30f; int bj = 0x7fffffff;
            if (tid < 256) {
                int j = tid;
                const float* qs = enc + (size_t)j * 64;
                float dkt = 0.f, dqt = 0.f, qq = 0.f, kk = 0.f;
                for (int c = 0; c < 64; ++c) {
                    float v = qs[c];
                    dkt = fmaf(kt[c], v, dkt);
                    dqt = fmaf(qt[c], v, dqt);
                    qq  = fmaf(v, v, qq);
                    kk  = fmaf(kt[c], kt[c], kk);
                }
                out[OFF_LOGITS_TS + (long long)i * 256 + j] = dqt * INV_T;
                bv = kk + qq - 2.f * dkt;
                bj = j;
            }
#pragma unroll
            for (int off = 32; off; off >>= 1) {
                float ov = __shfl_xor(bv, off, 64);
                int   oj = __shfl_xor(bj, off, 64);
                if (ov < bv || (ov == bv && oj < bj)) { bv = ov; bj = oj; }
            }
            int w = tid >> 6;
            if ((tid & 63) == 0) { swv[w] = bv; swj[w] = bj; }
            __syncthreads();
            if (tid == 0) {
                float best = swv[0]; int bi = swj[0];
#pragma unroll
                for (int k = 1; k < 8; ++k)
                    if (swv[k] < best || (swv[k] == best && swj[k] < bi)) { best = swv[k]; bi = swj[k]; }
                out[OFF_LABELS_TS + i] = (float)bi;
            }
        } else if (hb < 768) {
            __shared__ float xv[64];
            __shared__ float red[256];
            int r = hb - 256;
            const float* x = enc + ((r < 256) ? ((size_t)0 * B_SZ + r) : ((size_t)2 * B_SZ + (r - 256))) * 64;
            if (tid < 64) xv[tid] = x[tid];
            __syncthreads();
            if (tid < 256) {
                float h = db1[tid];
                for (int c = 0; c < 64; ++c) h = fmaf(xv[c], dw1[c * 256 + tid], h);
                h = fmaxf(h, 0.f);
                red[tid] = h * dw2[tid];
            }
            __syncthreads();
            for (int s2 = 128; s2; s2 >>= 1) {
                if (tid < s2) red[tid] += red[tid + s2];
                __syncthreads();
            }
            if (tid == 0) out[OFF_PRED_DOM + r] = red[0] + db2[0];
        } else if (hb < 1024) {
            __shared__ float xv[96];
            __shared__ float red[256];
            __shared__ float hsave[256];
            int b = hb - 768;
            if (tid < 64)       xv[tid] = enc[(size_t)b * 64 + tid];
            else if (tid < 96)  xv[tid] = stat[(size_t)b * 32 + (tid - 64)];
            __syncthreads();
            if (tid < 256) {
                float h = prb1[tid];
                for (int c = 0; c < 96; ++c) h = fmaf(xv[c], prw1[c * 256 + tid], h);
                hsave[tid] = fmaxf(h, 0.f);
            }
            __syncthreads();
            for (int o = 0; o < 2; ++o) {
                if (tid < 256) red[tid] = hsave[tid] * prw2[tid * 2 + o];
                __syncthreads();
                for (int s2 = 128; s2; s2 >>= 1) {
                    if (tid < s2) red[tid] += red[tid + s2];
                    __syncthreads();
                }
                if (tid == 0) out[OFF_YS + (long long)b * 2 + o] = red[0] + prb2[o];
                __syncthreads();
            }
        } else {
            int t = (hb - 1024) * 512 + tid;
            if (t < 256) {
                out[OFF_LABELS_S + t] = (float)t;
                out[OFF_LABELS_T + t] = (float)t;
            }
            if (t < 512) out[OFF_LABELS_DOM + t] = (t < 256) ? 1.f : 0.f;
        }
        return;
    }

    if (bx >= 384) {
        float (*pt)[65] = (float(*)[65])lds;
        int rt = bx - 384;
        const float* p = proj + ((size_t)sz * B_SZ + rt * 32) * 64;
        for (int idx = tid; idx < 32 * 64; idx += 512) {
            pt[idx >> 6][idx & 63] = p[idx];
        }
        __syncthreads();
        if (tid < 256) {
            float acc[32];
#pragma unroll
            for (int r = 0; r < 32; ++r) acc[r] = 0.f;
            int j = tid;
            const float* k = enc + ((size_t)(sz == 0 ? 1 : 3) * B_SZ + j) * 64;
            for (int c = 0; c < 64; ++c) {
                float bv = k[c];
#pragma unroll
                for (int r = 0; r < 32; ++r) acc[r] = fmaf(pt[r][c], bv, acc[r]);
            }
#pragma unroll
            for (int r = 0; r < 32; ++r) {
                out[outBase0 + (long long)(rt * 32 + r) * 24832 + j] = acc[r] * INV_T;
            }
        }
        return;
    }

    int j0 = bx * 64;
    const float* q = (sz == 0 ? queue_s : queue_t);
    {
#pragma unroll
        for (int pass = 0; pass < 2; ++pass) {
            int idx = pass * 512 + tid;
            int c = idx >> 4, jj0 = (idx & 15) * 4;
            float4 v = *(const float4*)(q + (size_t)c * KQ + j0 + jj0);
            float vv[4] = {v.x, v.y, v.z, v.w};
#pragma unroll
            for (int r = 0; r < 4; ++r) {
                int jj = jj0 + r;
                *(unsigned short*)(lds + jj * 128 + ((c * 2) ^ ((jj & 7) << 4))) = f2bf_rne(vv[r]);
            }
        }
    }
    __syncthreads();

    int w = tid >> 6, lane = tid & 63;
    int r31 = lane & 31, hi = lane >> 5;
    int arow = w * 32 + r31;
    const bf16x8* pa = (const bf16x8*)(pbf + ((size_t)sz * B_SZ + arow) * 64);
    bf16x8 A[4];
#pragma unroll
    for (int ks = 0; ks < 4; ++ks)
        A[ks] = pa[ks * 2 + hi];
    long long outBase = outBase0 + 256 + j0;
#pragma unroll
    for (int ct = 0; ct < 2; ++ct) {
        int col = ct * 32 + r31;
        bf16x8 Bf[4];
#pragma unroll
        for (int ks = 0; ks < 4; ++ks)
            Bf[ks] = *(const bf16x8*)(lds + col * 128 + (((ks * 16 + hi * 8) * 2) ^ ((col & 7) << 4)));
        floatx16 acc;
#pragma unroll
        for (int r = 0; r < 16; ++r) acc[r] = 0.f;
#pragma unroll
        for (int ks = 0; ks < 4; ++ks)
            acc = __builtin_amdgcn_mfma_f32_32x32x16_bf16(A[ks], Bf[ks], acc, 0, 0, 0);
#pragma unroll
        for (int r = 0; r < 16; ++r) {
            int drow = (r & 3) + 8 * (r >> 2) + 4 * hi;
            out[outBase + (long long)(w * 32 + drow) * 24832 + ct * 32 + r31] = acc[r] * INV_T;
        }
    }
}

// ---------------- launch ----------------
extern "C" void kernel_launch(void* const* d_in, const int* in_sizes, int n_in,
                              void* d_out, int out_size, void* d_ws, size_t ws_size,
                              hipStream_t stream) {
    const float* sqs    = (const float*)d_in[0];
    const float* sks    = (const float*)d_in[1];
    const float* stat_s = (const float*)d_in[2];
    const float* sqt    = (const float*)d_in[3];
    const float* skt    = (const float*)d_in[4];
    const float* c1w    = (const float*)d_in[7];
    const float* c1b    = (const float*)d_in[8];
    const float* c2w    = (const float*)d_in[9];
    const float* c2b    = (const float*)d_in[10];
    const float* pjw1   = (const float*)d_in[11];
    const float* pjb1   = (const float*)d_in[12];
    const float* pjw2   = (const float*)d_in[13];
    const float* pjb2   = (const float*)d_in[14];
    const float* prw1   = (const float*)d_in[15];
    const float* prb1   = (const float*)d_in[16];
    const float* prw2   = (const float*)d_in[17];
    const float* prb2   = (const float*)d_in[18];
    const float* dw1    = (const float*)d_in[19];
    const float* db1    = (const float*)d_in[20];
    const float* dw2    = (const float*)d_in[21];
    const float* db2    = (const float*)d_in[22];
    const float* queue_s = (const float*)d_in[23];
    const float* queue_t = (const float*)d_in[24];

    float* out = (float*)d_out;
    unsigned short* wf = (unsigned short*)d_ws;               // 491520 B
    float* enc  = (float*)((char*)d_ws + 491520);             // 4*256*64 floats
    float* proj = enc + 65536;                                // 2*256*64 floats
    unsigned short* pbf = (unsigned short*)(proj + 32768);    // 2*256*64 bf16

    prep_frag_kernel<<<240, 512, 0, stream>>>(c1w, c2w, wf);
    encode_kernel<<<dim3(256, 3), 256, 0, stream>>>(sqs, sks, sqt, skt, wf, c1b, c2b,
                                                    pjw1, pjb1, pjw2, pjb2, enc, proj, pbf);
    qlogits_kernel<<<dim3(905, 2), 512, 0, stream>>>(proj, pbf, enc, queue_s, queue_t,
                                                     stat_s, dw1, db1, dw2, db2,
                                                     prw1, prb1, prw2, prb2, out);
}

// Round 23
// 73.373 us; speedup vs baseline: 1.0447x; 1.0447x over previous
//
#include <hip/hip_runtime.h>
#include <hip/hip_bf16.h>

// ---------------- constants ----------------
#define B_SZ   256
#define L_SZ   1024
#define C_SZ   64
#define HID    256
#define KQ     24576
#define WIN    125          // receptive field of last position
#define WSTART (L_SZ - WIN) // 899

// output offsets (floats)
#define OFF_LOGITS_S   0LL
#define OFF_LABELS_S   6356992LL
#define OFF_LOGITS_T   6357248LL
#define OFF_LABELS_T   12714240LL
#define OFF_LOGITS_TS  12714496LL
#define OFF_LABELS_TS  12780032LL
#define OFF_PRED_DOM   12780288LL
#define OFF_LABELS_DOM 12780800LL
#define OFF_YS         12781312LL

#define INV_T (1.0f / 0.07f)

typedef __attribute__((ext_vector_type(8))) short  bf16x8;
typedef __attribute__((ext_vector_type(4))) float  floatx4;
typedef __attribute__((ext_vector_type(16))) float floatx16;
typedef __attribute__((ext_vector_type(4))) unsigned short ushortx4;

__device__ __forceinline__ unsigned short f2bf_rne(float x) {
    unsigned u = __float_as_uint(x);
    unsigned r = u + 0x7fffu + ((u >> 16) & 1u);
    return (unsigned short)(r >> 16);
}
__device__ __forceinline__ float bf2f(unsigned short h) {
    return __uint_as_float(((unsigned)h) << 16);
}

// stride-robust LDS swizzle: 2-way (free) for stride-1, conflict-free for stride-2
__device__ __forceinline__ int swz2(int r) { return ((r >> 1) & 7) << 4; }

// derive tap1 B-fragment from tap0/tap2 via DPP row shifts (verified R18):
// row_shl:1 -> dst[i]=src[i+1] (lane 15 invalid), row_shr:1 -> dst[i]=src[i-1] (lane 0 invalid).
// tap1[i] = tap0[i+1] for i<15; tap1[15] = tap2[14].
__device__ __forceinline__ bf16x8 dpp_tap1(bf16x8 f0, bf16x8 f2) {
    union U { bf16x8 v; int d[4]; } a, b, r;
    a.v = f0; b.v = f2;
#pragma unroll
    for (int k = 0; k < 4; ++k) {
        int patch = __builtin_amdgcn_update_dpp(0, b.d[k], 0x111, 0xf, 0xf, false);     // row_shr:1
        r.d[k]    = __builtin_amdgcn_update_dpp(patch, a.d[k], 0x101, 0xf, 0xf, false); // row_shl:1
    }
    return r.v;
}

// ---------------- weight A-fragment prep (16x16x32 layout) ----------------
__global__ void prep_frag_kernel(const float* __restrict__ c1w,
                                 const float* __restrict__ c2w,
                                 unsigned short* __restrict__ wf) {
    int bid = blockIdx.x;            // (st*3+tap)*8 + mt*2 + kb : 240 blocks
    int kb = bid & 1, mt = (bid >> 1) & 3;
    int sttap = bid >> 3;            // 0..29
    int tap = sttap % 3, st = sttap / 3;
    int l = st >> 1, cv = st & 1;
    int tid = threadIdx.x;           // 512
    int j = tid & 7, lane = tid >> 3;
    int co = mt * 16 + (lane & 15);
    int ci = kb * 32 + (lane >> 4) * 8 + j;
    const float* src = cv ? c2w : c1w;
    float w = src[((l * 64 + co) * 64 + ci) * 3 + tap];
    unsigned short hi = f2bf_rne(w);
    unsigned short lo = f2bf_rne(w - bf2f(hi));
    size_t b0 = ((((size_t)((st * 3 + tap) * 2 + 0)) * 4 + mt) * 2 + kb) * 512 + lane * 8 + j;
    size_t b1 = ((((size_t)((st * 3 + tap) * 2 + 1)) * 4 + mt) * 2 + kb) * 512 + lane * 8 + j;
    wf[b0] = hi;
    wf[b1] = lo;
}

// ---------------- TCN encode: precision-split (NH=2 hi/lo exact, NH=1 fast bf16) ----------------
#define R0H 0
#define R0L 16384
#define R1H 32768
#define R1L 40960
#define HHB 49152
#define HLB 65536
#define SCRATCH_B 57344

template<int NH>
__device__ __forceinline__ void loadAx(bf16x8 A[3][NH][2], const bf16x8* __restrict__ wf8,
                                       int st, int mt, int lane) {
#pragma unroll
    for (int tap = 0; tap < 3; ++tap)
#pragma unroll
        for (int h = 0; h < NH; ++h)
#pragma unroll
            for (int kb = 0; kb < 2; ++kb)
                A[tap][h][kb] = wf8[((((st * 3 + tap) * 2 + h) * 4 + mt) * 2 + kb) * 64 + lane];
}

template<int NH>
__device__ __forceinline__ void copyAx(bf16x8 D[3][NH][2], const bf16x8 S[3][NH][2]) {
#pragma unroll
    for (int tap = 0; tap < 3; ++tap)
#pragma unroll
        for (int h = 0; h < NH; ++h)
#pragma unroll
            for (int kb = 0; kb < 2; ++kb)
                D[tap][h][kb] = S[tap][h][kb];
}

template<int TILES, bool RES, bool FINAL, bool DPP1, int NH>
__device__ __forceinline__ void conv_pass(
    char* lds, const bf16x8 A[3][NH][2],
    int inH, int inL, int rows_valid, int stride,
    int outH, int outL, int n_out,
    int resH, int resL, int res_valid,
    const float* __restrict__ bias,
    int mt, int lg, int li)
{
    int co0 = mt * 16 + lg * 4;
    float4 b4 = *(const float4*)(bias + co0);
    float ba[4] = {b4.x, b4.y, b4.z, b4.w};

#pragma unroll
    for (int tt = 0; tt < TILES; ++tt) {
        int i = tt * 16 + li;
        floatx4 acc = {0.f, 0.f, 0.f, 0.f};
        if (DPP1) {
            int jr0 = i;       jr0 = (jr0 < rows_valid - 1) ? jr0 : (rows_valid - 1);
            int jr2 = i + 2;   jr2 = (jr2 < rows_valid - 1) ? jr2 : (rows_valid - 1);
            int sw0 = swz2(jr0), sw2 = swz2(jr2);
#pragma unroll
            for (int kb = 0; kb < 2; ++kb) {
                int cbase = kb * 64 + lg * 16;
                bf16x8 bH0 = *(const bf16x8*)(lds + inH + jr0 * 128 + (cbase ^ sw0));
                bf16x8 bH2 = *(const bf16x8*)(lds + inH + jr2 * 128 + (cbase ^ sw2));
                bf16x8 bH1 = dpp_tap1(bH0, bH2);
                acc = __builtin_amdgcn_mfma_f32_16x16x32_bf16(A[0][0][kb], bH0, acc, 0, 0, 0);
                acc = __builtin_amdgcn_mfma_f32_16x16x32_bf16(A[1][0][kb], bH1, acc, 0, 0, 0);
                acc = __builtin_amdgcn_mfma_f32_16x16x32_bf16(A[2][0][kb], bH2, acc, 0, 0, 0);
                if (NH == 2) {
                    bf16x8 bL0 = *(const bf16x8*)(lds + inL + jr0 * 128 + (cbase ^ sw0));
                    bf16x8 bL2 = *(const bf16x8*)(lds + inL + jr2 * 128 + (cbase ^ sw2));
                    bf16x8 bL1 = dpp_tap1(bL0, bL2);
                    acc = __builtin_amdgcn_mfma_f32_16x16x32_bf16(A[0][0][kb], bL0, acc, 0, 0, 0);
                    acc = __builtin_amdgcn_mfma_f32_16x16x32_bf16(A[0][NH-1][kb], bH0, acc, 0, 0, 0);
                    acc = __builtin_amdgcn_mfma_f32_16x16x32_bf16(A[1][0][kb], bL1, acc, 0, 0, 0);
                    acc = __builtin_amdgcn_mfma_f32_16x16x32_bf16(A[1][NH-1][kb], bH1, acc, 0, 0, 0);
                    acc = __builtin_amdgcn_mfma_f32_16x16x32_bf16(A[2][0][kb], bL2, acc, 0, 0, 0);
                    acc = __builtin_amdgcn_mfma_f32_16x16x32_bf16(A[2][NH-1][kb], bH2, acc, 0, 0, 0);
                }
            }
        } else {
#pragma unroll
            for (int tap = 0; tap < 3; ++tap) {
                int jr = i * stride + tap;
                jr = (jr < rows_valid - 1) ? jr : (rows_valid - 1);
                int sw = swz2(jr);
                const char* pH = lds + inH + jr * 128;
                const char* pL = lds + inL + jr * 128;
#pragma unroll
                for (int kb = 0; kb < 2; ++kb) {
                    int cb = (kb * 64 + lg * 16) ^ sw;
                    bf16x8 bH = *(const bf16x8*)(pH + cb);
                    acc = __builtin_amdgcn_mfma_f32_16x16x32_bf16(A[tap][0][kb], bH, acc, 0, 0, 0);
                    if (NH == 2) {
                        bf16x8 bL = *(const bf16x8*)(pL + cb);
                        acc = __builtin_amdgcn_mfma_f32_16x16x32_bf16(A[tap][0][kb], bL, acc, 0, 0, 0);
                        acc = __builtin_amdgcn_mfma_f32_16x16x32_bf16(A[tap][NH-1][kb], bH, acc, 0, 0, 0);
                    }
                }
            }
        }
        float v[4];
#pragma unroll
        for (int r = 0; r < 4; ++r) v[r] = fmaxf(acc[r] + ba[r], 0.f);
        if (RES) {
            int rr = 2 * i + 4;
            rr = (rr < res_valid - 1) ? rr : (res_valid - 1);
            int rsw = swz2(rr);
            int rcb = (mt * 32 + lg * 8) ^ rsw;
            ushortx4 rh = *(const ushortx4*)(lds + resH + rr * 128 + rcb);
            if (NH == 2) {
                ushortx4 rl = *(const ushortx4*)(lds + resL + rr * 128 + rcb);
#pragma unroll
                for (int r = 0; r < 4; ++r)
                    v[r] = fmaxf(v[r] + bf2f(rh[r]) + bf2f(rl[r]), 0.f);
            } else {
#pragma unroll
                for (int r = 0; r < 4; ++r)
                    v[r] = fmaxf(v[r] + bf2f(rh[r]), 0.f);
            }
        }
        if (FINAL) {
            if (i == 0) {
                float* scratch = (float*)(lds + SCRATCH_B);
#pragma unroll
                for (int r = 0; r < 4; ++r) scratch[co0 + r] = v[r];
            }
        } else {
            if (i < n_out) {
                int wsw = swz2(i);
                int wcb = (mt * 32 + lg * 8) ^ wsw;
                ushortx4 h4;
#pragma unroll
                for (int r = 0; r < 4; ++r) h4[r] = f2bf_rne(v[r]);
                *(ushortx4*)(lds + outH + i * 128 + wcb) = h4;
                if (NH == 2) {
                    ushortx4 l4;
#pragma unroll
                    for (int r = 0; r < 4; ++r) l4[r] = f2bf_rne(v[r] - bf2f(h4[r]));
                    *(ushortx4*)(lds + outL + i * 128 + wcb) = l4;
                }
            }
        }
    }
}

template<int NH>
__device__ __forceinline__ void encode_body(
    char* lds, const float* __restrict__ seq_base4_f,
    const bf16x8* __restrict__ wf8,
    const float* __restrict__ c1b, const float* __restrict__ c2b,
    int tid, int mt, int lane, int lg, int li)
{
    const float4* base4 = reinterpret_cast<const float4*>(seq_base4_f);

    bf16x8 A[3][NH][2], An[3][NH][2];
    loadAx<NH>(A, wf8, 0, mt, lane);

    // stage input: 125 rows x 64 ch -> bf16 (hi[/lo]), [t][ci], swizzled
    for (int idx = tid; idx < 2000; idx += 256) {
        float4 v = base4[idx];
        int t = idx >> 4, c0 = (idx & 15) * 4;
        int cb = (c0 * 2) ^ swz2(t);
        float vv[4] = {v.x, v.y, v.z, v.w};
        ushortx4 h4;
#pragma unroll
        for (int r = 0; r < 4; ++r) h4[r] = f2bf_rne(vv[r]);
        *(ushortx4*)(lds + R0H + t * 128 + cb) = h4;
        if (NH == 2) {
            ushortx4 l4;
#pragma unroll
            for (int r = 0; r < 4; ++r) l4[r] = f2bf_rne(vv[r] - bf2f(h4[r]));
            *(ushortx4*)(lds + R0L + t * 128 + cb) = l4;
        }
    }
    __syncthreads();

    // layer 0
    loadAx<NH>(An, wf8, 1, mt, lane);
    conv_pass<8, false, false, true, NH>(lds, A, R0H, R0L, 125, 1, HHB, HLB, 123, 0, 0, 0,
                                         c1b + 0, mt, lg, li);
    __syncthreads();
    copyAx<NH>(A, An); loadAx<NH>(An, wf8, 2, mt, lane);
    conv_pass<4, true, false, false, NH>(lds, A, HHB, HLB, 123, 2, R1H, R1L, 61, R0H, R0L, 125,
                                         c2b + 0, mt, lg, li);
    __syncthreads();
    copyAx<NH>(A, An);
    // layer 1
    loadAx<NH>(An, wf8, 3, mt, lane);
    conv_pass<4, false, false, true, NH>(lds, A, R1H, R1L, 61, 1, HHB, HLB, 59, 0, 0, 0,
                                         c1b + 64, mt, lg, li);
    __syncthreads();
    copyAx<NH>(A, An); loadAx<NH>(An, wf8, 4, mt, lane);
    conv_pass<2, true, false, false, NH>(lds, A, HHB, HLB, 59, 2, R0H, R0L, 29, R1H, R1L, 61,
                                         c2b + 64, mt, lg, li);
    __syncthreads();
    copyAx<NH>(A, An);
    // layer 2
    loadAx<NH>(An, wf8, 5, mt, lane);
    conv_pass<2, false, false, true, NH>(lds, A, R0H, R0L, 29, 1, HHB, HLB, 27, 0, 0, 0,
                                         c1b + 128, mt, lg, li);
    __syncthreads();
    copyAx<NH>(A, An); loadAx<NH>(An, wf8, 6, mt, lane);
    conv_pass<1, true, false, false, NH>(lds, A, HHB, HLB, 27, 2, R1H, R1L, 13, R0H, R0L, 29,
                                         c2b + 128, mt, lg, li);
    __syncthreads();
    copyAx<NH>(A, An);
    // layer 3
    loadAx<NH>(An, wf8, 7, mt, lane);
    conv_pass<1, false, false, true, NH>(lds, A, R1H, R1L, 13, 1, HHB, HLB, 11, 0, 0, 0,
                                         c1b + 192, mt, lg, li);
    __syncthreads();
    copyAx<NH>(A, An); loadAx<NH>(An, wf8, 8, mt, lane);
    conv_pass<1, true, false, false, NH>(lds, A, HHB, HLB, 11, 2, R0H, R0L, 5, R1H, R1L, 13,
                                         c2b + 192, mt, lg, li);
    __syncthreads();
    copyAx<NH>(A, An);
    // layer 4
    loadAx<NH>(An, wf8, 9, mt, lane);
    conv_pass<1, false, false, true, NH>(lds, A, R0H, R0L, 5, 1, HHB, HLB, 3, 0, 0, 0,
                                         c1b + 256, mt, lg, li);
    __syncthreads();
    copyAx<NH>(A, An);
    conv_pass<1, true, true, false, NH>(lds, A, HHB, HLB, 3, 2, R1H, R1L, 1, R0H, R0L, 5,
                                        c2b + 256, mt, lg, li);
    __syncthreads();
}

__launch_bounds__(256)
__global__ void encode_kernel(const float* __restrict__ sqs, const float* __restrict__ sks,
                              const float* __restrict__ sqt, const float* __restrict__ skt,
                              const unsigned short* __restrict__ wf,
                              const float* __restrict__ c1b, const float* __restrict__ c2b,
                              const float* __restrict__ pjw1, const float* __restrict__ pjb1,
                              const float* __restrict__ pjw2, const float* __restrict__ pjb2,
                              float* __restrict__ enc, float* __restrict__ proj,
                              unsigned short* __restrict__ pbf) {
    __shared__ char lds[81920];
    int b = blockIdx.x;
    // heavy-first dispatch: long (hi/lo) blocks s=0,3 launch before light s=1,2
    const int sord[4] = {0, 3, 1, 2};
    int s = sord[blockIdx.y];
    const float* seq = (s == 0) ? sqs : (s == 1) ? sks : (s == 2) ? sqt : skt;
    const float* base = seq + ((size_t)b * L_SZ + WSTART) * C_SZ;
    int tid = threadIdx.x;
    int mt   = tid >> 6;
    int lane = tid & 63;
    int lg = lane >> 4, li = lane & 15;
    const bf16x8* wf8 = (const bf16x8*)wf;

    // precision split: argmin consumes enc of s=0 (q_s) and s=3 (k_t) -> exact hi/lo path;
    // s=1 (k_s) and s=2 (q_t) feed only 5.1-threshold logits -> fast single-bf16 path.
    if (s == 0 || s == 3) {
        encode_body<2>(lds, base, wf8, c1b, c2b, tid, mt, lane, lg, li);
    } else {
        encode_body<1>(lds, base, wf8, c1b, c2b, tid, mt, lane, lg, li);
    }

    // ---- l2 normalize + write enc; keep normalized vector in LDS for fused proj ----
    float* xn = (float*)(lds + R0H);        // R0 dead after final pass
    if (tid < 64) {
        float vv = ((float*)(lds + SCRATCH_B))[tid];
        float sq = vv * vv;
#pragma unroll
        for (int off = 32; off; off >>= 1) sq += __shfl_xor(sq, off, 64);
        float norm = fmaxf(sqrtf(sq), 1e-12f);
        float nv = vv / norm;
        enc[((size_t)s * B_SZ + b) * 64 + tid] = nv;
        xn[tid] = nv;
    }
    __syncthreads();

    // ---- fused projection MLP + l2norm (only q_s / q_t blocks), 256 threads ----
    if (s == 0 || s == 2) {
        float* hv   = (float*)(lds + R1H);          // 256 floats
        float* red4 = (float*)(lds + R1H + 1024);   // 4 x 64 floats
        {
            float acc = pjb1[tid];
            const float* wcol = pjw1 + tid;
            for (int c = 0; c < 64; ++c) acc = fmaf(xn[c], wcol[c * 256], acc);
            hv[tid] = fmaxf(acc, 0.f);
        }
        __syncthreads();
        {
            int wv = tid >> 6, o = tid & 63;
            float acc = 0.f;
            const float* wcol = pjw2 + o;
            int j0 = wv * 64;
            for (int j = j0; j < j0 + 64; ++j) acc = fmaf(hv[j], wcol[j * 64], acc);
            red4[wv * 64 + o] = acc;
        }
        __syncthreads();
        if (tid < 64) {
            float o = pjb2[tid];
#pragma unroll
            for (int k = 0; k < 4; ++k) o += red4[k * 64 + tid];
            float sq = o * o;
#pragma unroll
            for (int off = 32; off; off >>= 1) sq += __shfl_xor(sq, off, 64);
            float norm = fmaxf(sqrtf(sq), 1e-12f);
            float pv = o / norm;
            int which = s >> 1;
            proj[((size_t)which * B_SZ + b) * 64 + tid] = pv;
            pbf[((size_t)which * B_SZ + b) * 64 + tid] = f2bf_rne(pv);
        }
    }
}

// ---------------- logits + heads fused kernel ----------------
// grid (905, 2), 512 threads:
//   bx < 384       : queue stripe MFMA (queue fetched exactly once)
//   bx in [384,392): k^T part, rt = bx-384
//   bx >= 392      : heads block hb = (bx-392) + sz*513
__launch_bounds__(512)
__global__ void qlogits_kernel(const float* __restrict__ proj,
                               const unsigned short* __restrict__ pbf,
                               const float* __restrict__ enc,
                               const float* __restrict__ queue_s, const float* __restrict__ queue_t,
                               const float* __restrict__ stat,
                               const float* __restrict__ dw1, const float* __restrict__ db1,
                               const float* __restrict__ dw2, const float* __restrict__ db2,
                               const float* __restrict__ prw1, const float* __restrict__ prb1,
                               const float* __restrict__ prw2, const float* __restrict__ prb2,
                               float* __restrict__ out) {
    __shared__ char lds[8448];          // queue stripe (8192 B) or kT pt[32][65] (8320 B)
    int bx = blockIdx.x;
    int sz = blockIdx.y;
    int tid = threadIdx.x;
    long long outBase0 = (sz == 0) ? OFF_LOGITS_S : OFF_LOGITS_T;

    if (bx >= 392) {
        // ================= heads =================
        int hb = (bx - 392) + sz * 513;
        if (hb < 256) {
            // ---- nn argmin + logits_ts ----
            __shared__ float kt[64];
            __shared__ float qt[64];
            __shared__ float swv[8];
            __shared__ int   swj[8];
            int i = hb;
            if (tid < 64) {
                kt[tid] = enc[((size_t)3 * B_SZ + i) * 64 + tid];
                qt[tid] = enc[((size_t)2 * B_SZ + i) * 64 + tid];
            }
            __syncthreads();
            float bv = 1e30f; int bj = 0x7fffffff;
            if (tid < 256) {
                int j = tid;
                const float* qs = enc + (size_t)j * 64;
                float dkt = 0.f, dqt = 0.f, qq = 0.f, kk = 0.f;
                for (int c = 0; c < 64; ++c) {
                    float v = qs[c];
                    dkt = fmaf(kt[c], v, dkt);
                    dqt = fmaf(qt[c], v, dqt);
                    qq  = fmaf(v, v, qq);
                    kk  = fmaf(kt[c], kt[c], kk);
                }
                out[OFF_LOGITS_TS + (long long)i * 256 + j] = dqt * INV_T;
                bv = kk + qq - 2.f * dkt;
                bj = j;
            }
#pragma unroll
            for (int off = 32; off; off >>= 1) {
                float ov = __shfl_xor(bv, off, 64);
                int   oj = __shfl_xor(bj, off, 64);
                if (ov < bv || (ov == bv && oj < bj)) { bv = ov; bj = oj; }
            }
            int w = tid >> 6;
            if ((tid & 63) == 0) { swv[w] = bv; swj[w] = bj; }
            __syncthreads();
            if (tid == 0) {
                float best = swv[0]; int bi = swj[0];
#pragma unroll
                for (int k = 1; k < 8; ++k)
                    if (swv[k] < best || (swv[k] == best && swj[k] < bi)) { best = swv[k]; bi = swj[k]; }
                out[OFF_LABELS_TS + i] = (float)bi;
            }
        } else if (hb < 768) {
            // ---- domain discriminator ----
            __shared__ float xv[64];
            __shared__ float red[256];
            int r = hb - 256;
            const float* x = enc + ((r < 256) ? ((size_t)0 * B_SZ + r) : ((size_t)2 * B_SZ + (r - 256))) * 64;
            if (tid < 64) xv[tid] = x[tid];
            __syncthreads();
            if (tid < 256) {
                float h = db1[tid];
                for (int c = 0; c < 64; ++c) h = fmaf(xv[c], dw1[c * 256 + tid], h);
                h = fmaxf(h, 0.f);
                red[tid] = h * dw2[tid];
            }
            __syncthreads();
            for (int s2 = 128; s2; s2 >>= 1) {
                if (tid < s2) red[tid] += red[tid + s2];
                __syncthreads();
            }
            if (tid == 0) out[OFF_PRED_DOM + r] = red[0] + db2[0];
        } else if (hb < 1024) {
            // ---- y_s head ----
            __shared__ float xv[96];
            __shared__ float red[256];
            __shared__ float hsave[256];
            int b = hb - 768;
            if (tid < 64)       xv[tid] = enc[(size_t)b * 64 + tid];
            else if (tid < 96)  xv[tid] = stat[(size_t)b * 32 + (tid - 64)];
            __syncthreads();
            if (tid < 256) {
                float h = prb1[tid];
                for (int c = 0; c < 96; ++c) h = fmaf(xv[c], prw1[c * 256 + tid], h);
                hsave[tid] = fmaxf(h, 0.f);
            }
            __syncthreads();
            for (int o = 0; o < 2; ++o) {
                if (tid < 256) red[tid] = hsave[tid] * prw2[tid * 2 + o];
                __syncthreads();
                for (int s2 = 128; s2; s2 >>= 1) {
                    if (tid < s2) red[tid] += red[tid + s2];
                    __syncthreads();
                }
                if (tid == 0) out[OFF_YS + (long long)b * 2 + o] = red[0] + prb2[o];
                __syncthreads();
            }
        } else {
            // ---- labels fill ----
            int t = (hb - 1024) * 512 + tid;
            if (t < 256) {
                out[OFF_LABELS_S + t] = (float)t;
                out[OFF_LABELS_T + t] = (float)t;
            }
            if (t < 512) out[OFF_LABELS_DOM + t] = (t < 256) ? 1.f : 0.f;
        }
        return;
    }

    if (bx >= 384) {
        // ---- k^T part ----
        float (*pt)[65] = (float(*)[65])lds;
        int rt = bx - 384;
        const float* p = proj + ((size_t)sz * B_SZ + rt * 32) * 64;
        for (int idx = tid; idx < 32 * 64; idx += 512) {
            pt[idx >> 6][idx & 63] = p[idx];
        }
        __syncthreads();
        if (tid < 256) {
            float acc[32];
#pragma unroll
            for (int r = 0; r < 32; ++r) acc[r] = 0.f;
            int j = tid;
            const float* k = enc + ((size_t)(sz == 0 ? 1 : 3) * B_SZ + j) * 64;
            for (int c = 0; c < 64; ++c) {
                float bv = k[c];
#pragma unroll
                for (int r = 0; r < 32; ++r) acc[r] = fmaf(pt[r][c], bv, acc[r]);
            }
#pragma unroll
            for (int r = 0; r < 32; ++r) {
                out[outBase0 + (long long)(rt * 32 + r) * 24832 + j] = acc[r] * INV_T;
            }
        }
        return;
    }

    // ---- queue part ----
    int j0 = bx * 64;
    const float* q = (sz == 0 ? queue_s : queue_t);

    {
#pragma unroll
        for (int pass = 0; pass < 2; ++pass) {
            int idx = pass * 512 + tid;          // 0..1023
            int c = idx >> 4, jj0 = (idx & 15) * 4;
            float4 v = *(const float4*)(q + (size_t)c * KQ + j0 + jj0);
            float vv[4] = {v.x, v.y, v.z, v.w};
#pragma unroll
            for (int r = 0; r < 4; ++r) {
                int jj = jj0 + r;
                *(unsigned short*)(lds + jj * 128 + ((c * 2) ^ ((jj & 7) << 4))) = f2bf_rne(vv[r]);
            }
        }
    }
    __syncthreads();

    int w = tid >> 6, lane = tid & 63;
    int r31 = lane & 31, hi = lane >> 5;
    int arow = w * 32 + r31;
    const bf16x8* pa = (const bf16x8*)(pbf + ((size_t)sz * B_SZ + arow) * 64);
    bf16x8 A[4];
#pragma unroll
    for (int ks = 0; ks < 4; ++ks)
        A[ks] = pa[ks * 2 + hi];
    long long outBase = outBase0 + 256 + j0;
#pragma unroll
    for (int ct = 0; ct < 2; ++ct) {
        int col = ct * 32 + r31;
        bf16x8 Bf[4];
#pragma unroll
        for (int ks = 0; ks < 4; ++ks)
            Bf[ks] = *(const bf16x8*)(lds + col * 128 + (((ks * 16 + hi * 8) * 2) ^ ((col & 7) << 4)));
        floatx16 acc;
#pragma unroll
        for (int r = 0; r < 16; ++r) acc[r] = 0.f;
#pragma unroll
        for (int ks = 0; ks < 4; ++ks)
            acc = __builtin_amdgcn_mfma_f32_32x32x16_bf16(A[ks], Bf[ks], acc, 0, 0, 0);
#pragma unroll
        for (int r = 0; r < 16; ++r) {
            int drow = (r & 3) + 8 * (r >> 2) + 4 * hi;
            out[outBase + (long long)(w * 32 + drow) * 24832 + ct * 32 + r31] = acc[r] * INV_T;
        }
    }
}

// ---------------- launch ----------------
extern "C" void kernel_launch(void* const* d_in, const int* in_sizes, int n_in,
                              void* d_out, int out_size, void* d_ws, size_t ws_size,
                              hipStream_t stream) {
    const float* sqs    = (const float*)d_in[0];
    const float* sks    = (const float*)d_in[1];
    const float* stat_s = (const float*)d_in[2];
    const float* sqt    = (const float*)d_in[3];
    const float* skt    = (const float*)d_in[4];
    const float* c1w    = (const float*)d_in[7];
    const float* c1b    = (const float*)d_in[8];
    const float* c2w    = (const float*)d_in[9];
    const float* c2b    = (const float*)d_in[10];
    const float* pjw1   = (const float*)d_in[11];
    const float* pjb1   = (const float*)d_in[12];
    const float* pjw2   = (const float*)d_in[13];
    const float* pjb2   = (const float*)d_in[14];
    const float* prw1   = (const float*)d_in[15];
    const float* prb1   = (const float*)d_in[16];
    const float* prw2   = (const float*)d_in[17];
    const float* prb2   = (const float*)d_in[18];
    const float* dw1    = (const float*)d_in[19];
    const float* db1    = (const float*)d_in[20];
    const float* dw2    = (const float*)d_in[21];
    const float* db2    = (const float*)d_in[22];
    const float* queue_s = (const float*)d_in[23];
    const float* queue_t = (const float*)d_in[24];

    float* out = (float*)d_out;
    unsigned short* wf = (unsigned short*)d_ws;               // 245760 halfs = 491520 B
    float* enc  = (float*)((char*)d_ws + 491520);             // 4*256*64 floats (262144 B)
    float* proj = enc + 65536;                                // 2*256*64 floats (131072 B)
    unsigned short* pbf = (unsigned short*)(proj + 32768);    // 2*256*64 bf16 (65536 B)

    prep_frag_kernel<<<240, 512, 0, stream>>>(c1w, c2w, wf);
    encode_kernel<<<dim3(256, 4), 256, 0, stream>>>(sqs, sks, sqt, skt, wf, c1b, c2b,
                                                    pjw1, pjb1, pjw2, pjb2, enc, proj, pbf);
    qlogits_kernel<<<dim3(905, 2), 512, 0, stream>>>(proj, pbf, enc, queue_s, queue_t,
                                                     stat_s, dw1, db1, dw2, db2,
                                                     prw1, prb1, prw2, prb2, out);
}